// Round 1
// baseline (75.804 us; speedup 1.0000x reference)
//
#include <hip/hip_runtime.h>
#include <cmath>

// x: (512,128) fp32. Per column the reference sorts 512 values and computes a
// 999-pt trapezoid of the Beta(0.6,0.4) pdf; loss = sum((pcdf-ecdf)^2)/512.
//
// Analytic reproduction of the trapezoid (identical math to the previous
// passing kernel, error << 1e-3 per element):
//   T(s) = I_s(0.6,0.4)  (exact regularized incomplete beta, CF)
//        - c_head * x1^0.6
//        + D_R (right-end trap-minus-exact over the last 8 intervals)
//
// CHANGE vs previous version: the bitonic sort (which forced 128 blocks x 512
// threads -> half the GPU idle, plus 45 compare-exchange stages and 12 extra
// __syncthreads) is replaced by RANK-BY-COUNTING: we only need each element's
// rank to pair T(v) with ecdf=(rank+1)/513. Rank = #{j : v_j < v_i or
// (v_j == v_i and j < i)} reproduces the stable sorted position exactly.
// This lets us launch 256 blocks x 256 threads (one block per CU, all 256 CUs
// active) with zero cross-wave communication: the column (2 KB) is staged in
// LDS and scanned with uniform-address float4 reads (broadcast, conflict-free).
#define N_ROWS 512
#define N_COLS 128

__device__ __forceinline__ float betacf(float a, float b, float x) {
    // Numerical Recipes continued fraction (modified Lentz), 16 double-steps.
    float qab = a + b, qap = a + 1.0f, qam = a - 1.0f;
    float c = 1.0f;
    float d = 1.0f - qab * x / qap;
    if (fabsf(d) < 1e-30f) d = 1e-30f;
    d = 1.0f / d;
    float h = d;
    #pragma unroll
    for (int m = 1; m <= 16; ++m) {
        float fm = (float)m, m2 = 2.0f * fm;
        float aa = fm * (b - fm) * x / ((qam + m2) * (a + m2));
        d = 1.0f + aa * d; if (fabsf(d) < 1e-30f) d = 1e-30f;
        c = 1.0f + aa / c; if (fabsf(c) < 1e-30f) c = 1e-30f;
        d = 1.0f / d;
        h *= d * c;
        aa = -(a + fm) * (qab + fm) * x / ((a + m2) * (qap + m2));
        d = 1.0f + aa * d; if (fabsf(d) < 1e-30f) d = 1e-30f;
        c = 1.0f + aa / c; if (fabsf(c) < 1e-30f) c = 1e-30f;
        d = 1.0f / d;
        h *= d * c;
    }
    return h;
}

// -------- Kernel 1: rank-by-counting fused with per-element pcdf-loss -------
// Block b handles column c = b>>1, rows [(b&1)*256, (b&1)*256+256).
__global__ __launch_bounds__(256, 1) void rank_loss(const float* __restrict__ x,
                                                    float* __restrict__ partials,
                                                    float lnB, float invB, float c_head) {
    __shared__ float col[N_ROWS];
    __shared__ float swave[4];
    const int tid = threadIdx.x;
    const int b   = blockIdx.x;
    const int c   = b >> 1;
    const int r   = ((b & 1) << 8) + tid;   // my global row in this column

    // stage full column into LDS (2 KB). Uncoalesced (stride 512B) but the
    // whole input is 256 KB -> L2-resident; cost is negligible.
    col[tid]       = x[tid * N_COLS + c];
    col[tid + 256] = x[(tid + 256) * N_COLS + c];
    __syncthreads();

    const float v = col[r];

    // rank = # of (value,index) pairs strictly below (v, r).
    // Uniform LDS addresses across the wave -> broadcast reads, no conflicts.
    int cnt = 0;
    const float4* col4 = (const float4*)col;
    #pragma unroll 8
    for (int i4 = 0; i4 < N_ROWS / 4; ++i4) {
        const float4 q = col4[i4];
        const int base = i4 << 2;
        cnt += (q.x < v) || ((q.x == v) && (base     < r));
        cnt += (q.y < v) || ((q.y == v) && (base + 1 < r));
        cnt += (q.z < v) || ((q.z == v) && (base + 2 < r));
        cnt += (q.w < v) || ((q.w == v) && (base + 3 < r));
    }

    // ---- per-element analytic T(s): identical math to previous version ----
    const float s  = fmaxf(v, 1e-30f);
    const float sm = s - 1e-10f;
    const float h  = sm * (1.0f / 999.0f);
    const float x1 = 1e-10f + h;

    // exact regularized incomplete beta I_s(0.6,0.4)
    const float ls  = __logf(s);
    const float om  = fmaxf(1.0f - s, 1e-30f);
    const float lom = __logf(om);
    const float bt  = __expf(fmaf(0.6f, ls, fmaf(0.4f, lom, -lnB)));
    float I;
    if (s < 0.53333333f)
        I = bt * betacf(0.6f, 0.4f, s) * (1.0f / 0.6f);
    else
        I = 1.0f - bt * betacf(0.4f, 0.6f, om) * (1.0f / 0.4f);

    // head correction
    const float head = c_head * __expf(0.6f * __logf(x1));

    // right-end trapezoid-vs-exact, last 8 intervals
    const float sm04 = __expf(-0.4f * ls);             // s^{-0.4}
    float wp      = om;                                // w_0 = 1 - s
    float wp_m06  = __expf(-0.6f * __logf(wp));
    float wp_p04  = wp * wp_m06;                       // w^{0.4}
    float dr = 0.0f;
    #pragma unroll
    for (int j = 1; j <= 8; ++j) {
        float w    = fmaf((float)j, h, om);
        float wm06 = __expf(-0.6f * __logf(w));
        float wp04 = w * wm06;
        float trap = 0.5f * h * (wp_m06 + wm06);
        float ex   = (wp04 - wp_p04) * 2.5f;           // /0.4
        dr += trap - ex;
        wp_m06 = wm06; wp_p04 = wp04;
    }
    dr *= sm04 * invB;

    const float T    = I - head + dr;
    const float ecdf = (float)(cnt + 1) * (1.0f / 513.0f);
    const float d    = T - ecdf;
    float val = d * d;

    // block reduction (4 waves)
    #pragma unroll
    for (int off = 32; off > 0; off >>= 1)
        val += __shfl_down(val, off);
    if ((tid & 63) == 0) swave[tid >> 6] = val;
    __syncthreads();
    if (tid == 0)
        partials[b] = swave[0] + swave[1] + swave[2] + swave[3];
}

// -------- Kernel 2: reduce 256 partials -> loss -----------------------------
__global__ __launch_bounds__(64) void reduce_partials(const float* __restrict__ partials,
                                                      float* __restrict__ out) {
    const int tid = threadIdx.x;
    float acc = partials[tid] + partials[tid + 64] + partials[tid + 128] + partials[tid + 192];
    #pragma unroll
    for (int off = 32; off > 0; off >>= 1)
        acc += __shfl_down(acc, off);
    if (tid == 0)
        out[0] = acc * (1.0f / (float)N_ROWS);
}

extern "C" void kernel_launch(void* const* d_in, const int* in_sizes, int n_in,
                              void* d_out, int out_size, void* d_ws, size_t ws_size,
                              hipStream_t stream) {
    const float* x = (const float*)d_in[0];
    float* out = (float*)d_out;
    float* partials = (float*)d_ws;   // 256 floats

    const double B = exp(lgamma(0.6) + lgamma(0.4) - lgamma(1.0));  // 3.3034443
    const float lnB    = (float)log(B);
    const float invB   = (float)(1.0 / B);
    // head coeff: I(x1) ~ x1^0.6/(0.6B) minus left-end trap excess 0.03185*x1^0.6/B
    const float c_head = (float)(1.0 / (0.6 * B) - 0.03185 / B);

    rank_loss<<<2 * N_COLS, 256, 0, stream>>>(x, partials, lnB, invB, c_head);
    reduce_partials<<<1, 64, 0, stream>>>(partials, out);
}

// Round 2
// 65.015 us; speedup vs baseline: 1.1659x; 1.1659x over previous
//
#include <hip/hip_runtime.h>
#include <cmath>

// x: (512,128) fp32. Per column: sort 512; reference computes a 999-pt trapezoid
// of the Beta(0.6,0.4) pdf from x1=EPS+h to s (h=(s-EPS)/999, t=0 dropped);
// loss = sum((pcdf-ecdf)^2)/512, threshold 4.875e-2 absolute.
//
// Analytic reproduction of the trapezoid (error << 1e-3 per element):
//   T(s) = I_s(0.6,0.4)                      exact regularized incomplete beta (CF)
//        - c_head * x1^0.6                   head correction
//        + D_R                               right-end trap-minus-exact, last 8 intervals
//
// R1 post-mortem: rank-by-counting (O(n^2) scan, 256x256) regressed 8 us vs the
// bitonic sort -> reverted to the sort structure.
// R2 change: BRANCHLESS single betacf call. The old code's if/else around
// betacf(0.6,0.4,s) vs betacf(0.4,0.6,1-s) diverges in every wave (uniform
// random data), so the ~200-instr CF body executed twice serially under exec
// masking. Selecting (a,b,x) per lane and calling betacf once is bit-identical
// per lane and halves the dominant compute.
#define N_ROWS 512
#define N_COLS 128

__device__ __forceinline__ float betacf(float a, float b, float x) {
    // Numerical Recipes continued fraction (modified Lentz), 16 double-steps.
    float qab = a + b, qap = a + 1.0f, qam = a - 1.0f;
    float c = 1.0f;
    float d = 1.0f - qab * x / qap;
    if (fabsf(d) < 1e-30f) d = 1e-30f;
    d = 1.0f / d;
    float h = d;
    #pragma unroll
    for (int m = 1; m <= 16; ++m) {
        float fm = (float)m, m2 = 2.0f * fm;
        float aa = fm * (b - fm) * x / ((qam + m2) * (a + m2));
        d = 1.0f + aa * d; if (fabsf(d) < 1e-30f) d = 1e-30f;
        c = 1.0f + aa / c; if (fabsf(c) < 1e-30f) c = 1e-30f;
        d = 1.0f / d;
        h *= d * c;
        aa = -(a + fm) * (qab + fm) * x / ((a + m2) * (qap + m2));
        d = 1.0f + aa * d; if (fabsf(d) < 1e-30f) d = 1e-30f;
        c = 1.0f + aa / c; if (fabsf(c) < 1e-30f) c = 1e-30f;
        d = 1.0f / d;
        h *= d * c;
    }
    return h;
}

// -------- Kernel 1: bitonic sort per column fused with per-element pcdf-loss
__global__ __launch_bounds__(512) void sort_loss(const float* __restrict__ x,
                                                 float* __restrict__ partials,
                                                 float lnB, float invB, float c_head) {
    __shared__ float sd[N_ROWS];
    const int tid = threadIdx.x;
    const int col = blockIdx.x;
    float v = x[tid * N_COLS + col];
    for (int k = 2; k <= N_ROWS; k <<= 1) {
        for (int j = k >> 1; j > 0; j >>= 1) {
            float pv;
            if (j >= 64) {                 // cross-wave: via LDS
                __syncthreads();
                sd[tid] = v;
                __syncthreads();
                pv = sd[tid ^ j];
            } else {                       // in-wave: shuffle
                pv = __shfl_xor(v, j, 64);
            }
            const bool lower = (tid & j) == 0;
            const bool asc   = (tid & k) == 0;
            v = (lower == asc) ? fminf(v, pv) : fmaxf(v, pv);
        }
    }
    // v = sorted value at rank `tid` of column `col`.
    const float s  = fmaxf(v, 1e-30f);
    const float sm = s - 1e-10f;
    const float h  = sm * (1.0f / 999.0f);
    const float x1 = 1e-10f + h;

    // exact regularized incomplete beta I_s(0.6,0.4)
    const float ls  = __logf(s);
    const float om  = fmaxf(1.0f - s, 1e-30f);
    const float lom = __logf(om);
    const float bt  = __expf(fmaf(0.6f, ls, fmaf(0.4f, lom, -lnB)));

    // Branchless argument select -> SINGLE betacf call (no divergent dual
    // execution of the ~200-instr CF body). Bit-identical per lane to the
    // old if/else version.
    const bool lo = s < 0.53333333f;
    const float ca = lo ? 0.6f : 0.4f;
    const float cb = lo ? 0.4f : 0.6f;
    const float cx = lo ? s : om;
    const float cf = betacf(ca, cb, cx);
    const float I  = lo ? bt * cf * (1.0f / 0.6f)
                        : 1.0f - bt * cf * (1.0f / 0.4f);

    // head correction
    const float head = c_head * __expf(0.6f * __logf(x1));

    // right-end trapezoid-vs-exact, last 8 intervals
    const float sm04 = __expf(-0.4f * ls);             // s^{-0.4}
    float wp      = om;                                // w_0 = 1 - s
    float wp_m06  = __expf(-0.6f * __logf(wp));
    float wp_p04  = wp * wp_m06;                       // w^{0.4}
    float dr = 0.0f;
    #pragma unroll
    for (int j = 1; j <= 8; ++j) {
        float w    = fmaf((float)j, h, om);
        float wm06 = __expf(-0.6f * __logf(w));
        float wp04 = w * wm06;
        float trap = 0.5f * h * (wp_m06 + wm06);
        float ex   = (wp04 - wp_p04) * 2.5f;           // /0.4
        dr += trap - ex;
        wp_m06 = wm06; wp_p04 = wp04;
    }
    dr *= sm04 * invB;

    const float T    = I - head + dr;
    const float ecdf = (float)(tid + 1) * (1.0f / 513.0f);
    const float d    = T - ecdf;
    float val = d * d;

    // block reduction (8 waves)
    #pragma unroll
    for (int off = 32; off > 0; off >>= 1)
        val += __shfl_down(val, off);
    __syncthreads();                                   // sd reuse
    if ((tid & 63) == 0) sd[tid >> 6] = val;
    __syncthreads();
    if (tid == 0) {
        float bs = 0.0f;
        #pragma unroll
        for (int w = 0; w < 8; ++w) bs += sd[w];
        partials[col] = bs;
    }
}

// -------- Kernel 2: reduce 128 partials -> loss -----------------------------
__global__ __launch_bounds__(64) void reduce_partials(const float* __restrict__ partials,
                                                      float* __restrict__ out) {
    float acc = partials[threadIdx.x] + partials[threadIdx.x + 64];
    #pragma unroll
    for (int off = 32; off > 0; off >>= 1)
        acc += __shfl_down(acc, off);
    if (threadIdx.x == 0)
        out[0] = acc * (1.0f / (float)N_ROWS);
}

extern "C" void kernel_launch(void* const* d_in, const int* in_sizes, int n_in,
                              void* d_out, int out_size, void* d_ws, size_t ws_size,
                              hipStream_t stream) {
    const float* x = (const float*)d_in[0];
    float* out = (float*)d_out;
    float* partials = (float*)d_ws;   // 128 floats

    const double B = exp(lgamma(0.6) + lgamma(0.4) - lgamma(1.0));  // 3.3034443
    const float lnB    = (float)log(B);
    const float invB   = (float)(1.0 / B);
    // head coeff: I(x1) ~ x1^0.6/(0.6B) minus left-end trap excess 0.03185*x1^0.6/B
    const float c_head = (float)(1.0 / (0.6 * B) - 0.03185 / B);

    sort_loss<<<N_COLS, N_ROWS, 0, stream>>>(x, partials, lnB, invB, c_head);
    reduce_partials<<<1, 64, 0, stream>>>(partials, out);
}

// Round 3
// 63.992 us; speedup vs baseline: 1.1846x; 1.0160x over previous
//
#include <hip/hip_runtime.h>
#include <cmath>

// x: (512,128) fp32. Per column: sort 512; reference computes a 999-pt trapezoid
// of the Beta(0.6,0.4) pdf from x1=EPS+h to s (h=(s-EPS)/999, t=0 dropped);
// loss = sum((pcdf-ecdf)^2)/512, threshold 4.875e-2 absolute.
//
// Analytic reproduction of the trapezoid (error << 1e-3 per element):
//   T(s) = I_s(0.6,0.4)                      exact regularized incomplete beta (CF)
//        - c_head * x1^0.6                   head correction
//        + D_R                               right-end trap-minus-exact, last 8 intervals
//
// R1: rank-by-counting regressed (O(n^2) scan) -> reverted to bitonic sort.
// R2: branchless single betacf call: -2.8 us (calibrates one 16-double-step CF
//     execution ~ 2.8 us of wall).
// R3: (a) reduce_partials kernel node removed -- 4-byte memset node + per-block
//     atomicAdd(out, bs/512). Two dispatches -> one kernel + one memset; the
//     ~15-20 us unexplained gap (65 - 40 us fill - ~5 us compute) is dispatch
//     overhead, and this removes the biggest controllable piece of it.
//     (b) betacf cut 16 -> 6 double-steps: CF convergence factor per
//     double-step <= 0.036 at x <= 0.5333 -> truncation ~1e-8, saves ~1.7 us
//     of the serial chain.
#define N_ROWS 512
#define N_COLS 128

__device__ __forceinline__ float betacf(float a, float b, float x) {
    // Numerical Recipes continued fraction (modified Lentz), 6 double-steps.
    // Convergence ratio per term rho = (1-sqrt(1-x))/(1+sqrt(1-x)) <= 0.19 for
    // x <= 0.5333 -> error after 6 double-steps ~ rho^12 < 1e-8.
    float qab = a + b, qap = a + 1.0f, qam = a - 1.0f;
    float c = 1.0f;
    float d = 1.0f - qab * x / qap;
    if (fabsf(d) < 1e-30f) d = 1e-30f;
    d = 1.0f / d;
    float h = d;
    #pragma unroll
    for (int m = 1; m <= 6; ++m) {
        float fm = (float)m, m2 = 2.0f * fm;
        float aa = fm * (b - fm) * x / ((qam + m2) * (a + m2));
        d = 1.0f + aa * d; if (fabsf(d) < 1e-30f) d = 1e-30f;
        c = 1.0f + aa / c; if (fabsf(c) < 1e-30f) c = 1e-30f;
        d = 1.0f / d;
        h *= d * c;
        aa = -(a + fm) * (qab + fm) * x / ((a + m2) * (qap + m2));
        d = 1.0f + aa * d; if (fabsf(d) < 1e-30f) d = 1e-30f;
        c = 1.0f + aa / c; if (fabsf(c) < 1e-30f) c = 1e-30f;
        d = 1.0f / d;
        h *= d * c;
    }
    return h;
}

// -------- Single kernel: bitonic sort + per-element pcdf-loss + atomic out --
__global__ __launch_bounds__(512) void sort_loss(const float* __restrict__ x,
                                                 float* __restrict__ out,
                                                 float lnB, float invB, float c_head) {
    __shared__ float sd[N_ROWS];
    const int tid = threadIdx.x;
    const int col = blockIdx.x;
    float v = x[tid * N_COLS + col];
    for (int k = 2; k <= N_ROWS; k <<= 1) {
        for (int j = k >> 1; j > 0; j >>= 1) {
            float pv;
            if (j >= 64) {                 // cross-wave: via LDS
                __syncthreads();
                sd[tid] = v;
                __syncthreads();
                pv = sd[tid ^ j];
            } else {                       // in-wave: shuffle
                pv = __shfl_xor(v, j, 64);
            }
            const bool lower = (tid & j) == 0;
            const bool asc   = (tid & k) == 0;
            v = (lower == asc) ? fminf(v, pv) : fmaxf(v, pv);
        }
    }
    // v = sorted value at rank `tid` of column `col`.
    const float s  = fmaxf(v, 1e-30f);
    const float sm = s - 1e-10f;
    const float h  = sm * (1.0f / 999.0f);
    const float x1 = 1e-10f + h;

    // exact regularized incomplete beta I_s(0.6,0.4)
    const float ls  = __logf(s);
    const float om  = fmaxf(1.0f - s, 1e-30f);
    const float lom = __logf(om);
    const float bt  = __expf(fmaf(0.6f, ls, fmaf(0.4f, lom, -lnB)));

    // Branchless argument select -> single betacf call.
    const bool lo = s < 0.53333333f;
    const float ca = lo ? 0.6f : 0.4f;
    const float cb = lo ? 0.4f : 0.6f;
    const float cx = lo ? s : om;
    const float cf = betacf(ca, cb, cx);
    const float I  = lo ? bt * cf * (1.0f / 0.6f)
                        : 1.0f - bt * cf * (1.0f / 0.4f);

    // head correction
    const float head = c_head * __expf(0.6f * __logf(x1));

    // right-end trapezoid-vs-exact, last 8 intervals
    const float sm04 = __expf(-0.4f * ls);             // s^{-0.4}
    float wp      = om;                                // w_0 = 1 - s
    float wp_m06  = __expf(-0.6f * __logf(wp));
    float wp_p04  = wp * wp_m06;                       // w^{0.4}
    float dr = 0.0f;
    #pragma unroll
    for (int j = 1; j <= 8; ++j) {
        float w    = fmaf((float)j, h, om);
        float wm06 = __expf(-0.6f * __logf(w));
        float wp04 = w * wm06;
        float trap = 0.5f * h * (wp_m06 + wm06);
        float ex   = (wp04 - wp_p04) * 2.5f;           // /0.4
        dr += trap - ex;
        wp_m06 = wm06; wp_p04 = wp04;
    }
    dr *= sm04 * invB;

    const float T    = I - head + dr;
    const float ecdf = (float)(tid + 1) * (1.0f / 513.0f);
    const float d    = T - ecdf;
    float val = d * d;

    // block reduction (8 waves)
    #pragma unroll
    for (int off = 32; off > 0; off >>= 1)
        val += __shfl_down(val, off);
    __syncthreads();                                   // sd reuse
    if ((tid & 63) == 0) sd[tid >> 6] = val;
    __syncthreads();
    if (tid == 0) {
        float bs = 0.0f;
        #pragma unroll
        for (int w = 0; w < 8; ++w) bs += sd[w];
        atomicAdd(out, bs * (1.0f / (float)N_ROWS));   // out pre-zeroed by memset node
    }
}

extern "C" void kernel_launch(void* const* d_in, const int* in_sizes, int n_in,
                              void* d_out, int out_size, void* d_ws, size_t ws_size,
                              hipStream_t stream) {
    const float* x = (const float*)d_in[0];
    float* out = (float*)d_out;

    const double B = exp(lgamma(0.6) + lgamma(0.4) - lgamma(1.0));  // 3.3034443
    const float lnB    = (float)log(B);
    const float invB   = (float)(1.0 / B);
    // head coeff: I(x1) ~ x1^0.6/(0.6B) minus left-end trap excess 0.03185*x1^0.6/B
    const float c_head = (float)(1.0 / (0.6 * B) - 0.03185 / B);

    // zero the scalar output (memset node is far cheaper than a kernel node),
    // then a single fused kernel accumulates into it atomically.
    hipMemsetAsync(d_out, 0, sizeof(float), stream);
    sort_loss<<<N_COLS, N_ROWS, 0, stream>>>(x, out, lnB, invB, c_head);
}

// Round 4
// 61.567 us; speedup vs baseline: 1.2312x; 1.0394x over previous
//
#include <hip/hip_runtime.h>
#include <cmath>

// x: (512,128) fp32. Per column: sort 512; reference computes a 999-pt trapezoid
// of the Beta(0.6,0.4) pdf from x1=EPS+h to s (h=(s-EPS)/999, t=0 dropped);
// loss = sum((pcdf-ecdf)^2)/512, threshold 4.875e-2 absolute.
//
// Analytic reproduction of the trapezoid:
//   T(s) = I_s(0.6,0.4)                      exact regularized incomplete beta (CF)
//        - c_head * x1^0.6                   head correction
//        + D_R                               right-end trap-minus-exact correction
//
// R1: rank-by-counting regressed -> reverted to bitonic sort.
// R2: branchless single betacf: -2.8 us (one full 16-double-step CF ~ 2.8 us wall).
// R3: fused atomic output (node removal ~0 gain -> node overhead ~0.5us, not 10);
//     CF 16->6: -1 us. Decomposition: ~39.7us poison fill (harness, HBM-bound)
//     + ~19us fixed reset/graph overhead + ~4-5us kernel (controllable).
// R4: trim the serial math chain:
//     (a) CF 6->4 double-steps (rho^8 <= 1.6e-6 truncation).
//     (b) D_R 8->4 intervals with telescoped exact term: needs only
//         f_j = w_j^-0.6, j=0..4 (f_0 reuses log(om)) -> 4 log/exp pairs
//         instead of 9+... ; dropped-interval residual ~2e-5 worst element,
//         per-element budget ~1e-4.
#define N_ROWS 512
#define N_COLS 128

__device__ __forceinline__ float betacf(float a, float b, float x) {
    // Numerical Recipes continued fraction (modified Lentz), 4 double-steps.
    // rho = (1-sqrt(1-x))/(1+sqrt(1-x)) <= 0.188 for x <= 0.5333
    // -> truncation ~ rho^8 ~ 1.6e-6.
    float qab = a + b, qap = a + 1.0f, qam = a - 1.0f;
    float c = 1.0f;
    float d = 1.0f - qab * x / qap;
    if (fabsf(d) < 1e-30f) d = 1e-30f;
    d = 1.0f / d;
    float h = d;
    #pragma unroll
    for (int m = 1; m <= 4; ++m) {
        float fm = (float)m, m2 = 2.0f * fm;
        float aa = fm * (b - fm) * x / ((qam + m2) * (a + m2));
        d = 1.0f + aa * d; if (fabsf(d) < 1e-30f) d = 1e-30f;
        c = 1.0f + aa / c; if (fabsf(c) < 1e-30f) c = 1e-30f;
        d = 1.0f / d;
        h *= d * c;
        aa = -(a + fm) * (qab + fm) * x / ((a + m2) * (qap + m2));
        d = 1.0f + aa * d; if (fabsf(d) < 1e-30f) d = 1e-30f;
        c = 1.0f + aa / c; if (fabsf(c) < 1e-30f) c = 1e-30f;
        d = 1.0f / d;
        h *= d * c;
    }
    return h;
}

// -------- Single kernel: bitonic sort + per-element pcdf-loss + atomic out --
__global__ __launch_bounds__(512) void sort_loss(const float* __restrict__ x,
                                                 float* __restrict__ out,
                                                 float lnB, float invB, float c_head) {
    __shared__ float sd[N_ROWS];
    const int tid = threadIdx.x;
    const int col = blockIdx.x;
    float v = x[tid * N_COLS + col];
    for (int k = 2; k <= N_ROWS; k <<= 1) {
        for (int j = k >> 1; j > 0; j >>= 1) {
            float pv;
            if (j >= 64) {                 // cross-wave: via LDS
                __syncthreads();
                sd[tid] = v;
                __syncthreads();
                pv = sd[tid ^ j];
            } else {                       // in-wave: shuffle
                pv = __shfl_xor(v, j, 64);
            }
            const bool lower = (tid & j) == 0;
            const bool asc   = (tid & k) == 0;
            v = (lower == asc) ? fminf(v, pv) : fmaxf(v, pv);
        }
    }
    // v = sorted value at rank `tid` of column `col`.
    const float s  = fmaxf(v, 1e-30f);
    const float sm = s - 1e-10f;
    const float h  = sm * (1.0f / 999.0f);
    const float x1 = 1e-10f + h;

    // exact regularized incomplete beta I_s(0.6,0.4)
    const float ls  = __logf(s);
    const float om  = fmaxf(1.0f - s, 1e-30f);
    const float lom = __logf(om);
    const float bt  = __expf(fmaf(0.6f, ls, fmaf(0.4f, lom, -lnB)));

    // Branchless argument select -> single betacf call.
    const bool lo = s < 0.53333333f;
    const float ca = lo ? 0.6f : 0.4f;
    const float cb = lo ? 0.4f : 0.6f;
    const float cx = lo ? s : om;
    const float cf = betacf(ca, cb, cx);
    const float I  = lo ? bt * cf * (1.0f / 0.6f)
                        : 1.0f - bt * cf * (1.0f / 0.4f);

    // head correction
    const float head = c_head * __expf(0.6f * __logf(x1));

    // right-end trapezoid-vs-exact over the last 4 intervals, telescoped:
    // D_R = s^-0.4/B * [ h*(f0/2 + f1 + f2 + f3 + f4/2) - (w4^0.4 - w0^0.4)*2.5 ]
    // with f_j = w_j^-0.6, w_j = om + j*h.  f0 reuses lom.
    const float sm04 = __expf(-0.4f * ls);             // s^{-0.4}
    const float f0   = __expf(-0.6f * lom);            // om^{-0.6}
    const float f1   = __expf(-0.6f * __logf(fmaf(1.0f, h, om)));
    const float f2   = __expf(-0.6f * __logf(fmaf(2.0f, h, om)));
    const float f3   = __expf(-0.6f * __logf(fmaf(3.0f, h, om)));
    const float w4   = fmaf(4.0f, h, om);
    const float f4   = __expf(-0.6f * __logf(w4));
    const float fsum = fmaf(0.5f, f0, f1) + f2 + fmaf(0.5f, f4, f3);
    const float w4p  = w4 * f4;                        // w4^{0.4}
    const float w0p  = om * f0;                        // om^{0.4}
    const float dr   = (h * fsum - (w4p - w0p) * 2.5f) * sm04 * invB;

    const float T    = I - head + dr;
    const float ecdf = (float)(tid + 1) * (1.0f / 513.0f);
    const float d    = T - ecdf;
    float val = d * d;

    // block reduction (8 waves)
    #pragma unroll
    for (int off = 32; off > 0; off >>= 1)
        val += __shfl_down(val, off);
    __syncthreads();                                   // sd reuse
    if ((tid & 63) == 0) sd[tid >> 6] = val;
    __syncthreads();
    if (tid == 0) {
        float bs = 0.0f;
        #pragma unroll
        for (int w = 0; w < 8; ++w) bs += sd[w];
        atomicAdd(out, bs * (1.0f / (float)N_ROWS));   // out pre-zeroed by memset node
    }
}

extern "C" void kernel_launch(void* const* d_in, const int* in_sizes, int n_in,
                              void* d_out, int out_size, void* d_ws, size_t ws_size,
                              hipStream_t stream) {
    const float* x = (const float*)d_in[0];
    float* out = (float*)d_out;

    const double B = exp(lgamma(0.6) + lgamma(0.4) - lgamma(1.0));  // 3.3034443
    const float lnB    = (float)log(B);
    const float invB   = (float)(1.0 / B);
    // head coeff: I(x1) ~ x1^0.6/(0.6B) minus left-end trap excess 0.03185*x1^0.6/B
    const float c_head = (float)(1.0 / (0.6 * B) - 0.03185 / B);

    hipMemsetAsync(d_out, 0, sizeof(float), stream);
    sort_loss<<<N_COLS, N_ROWS, 0, stream>>>(x, out, lnB, invB, c_head);
}